// Round 7
// baseline (299.077 us; speedup 1.0000x reference)
//
#include <hip/hip_runtime.h>
#include <math.h>

#define NN 50000
#define EE 800000
#define RR 2
#define LL 2
#define DD 128
#define GG 64
#define CCLS 8
#define NBUK 196     // buckets of 256 dst nodes: bucket = dst >> 8
#define BCAP 4608    // max raw edges per bucket per relation (mean 4082, sigma 64; +8 sigma)
#define BCI  12000   // per-bucket CSR slots (r0,r1 each padded to %8 per node, +32 tail)

typedef unsigned int uint;
typedef unsigned short ushort;
typedef short bf16x8 __attribute__((ext_vector_type(8)));
typedef float f32x4 __attribute__((ext_vector_type(4)));
typedef float f32x2 __attribute__((ext_vector_type(2)));

// ---------------- workspace layout (bytes), total 42,575,936 ----------------
#define OFF_AGG   ((size_t)0)            // agg [N][256] bf16             25,600,000
                                         //  (bdata [2][196][BCAP] uint 7,225,344 ALIASES
                                         //   this region; dead after k_csr2.
                                         //   gemm-l1 packs h into agg rows in place.)
#define OFF_WBT   ((size_t)25600000)     // Ws [L][128 n][256 k] bf16        131,072
#define OFF_ISD   ((size_t)25731072)     // [2][N] f32                       400,000
#define OFF_RP    ((size_t)26131072)     // rps/rpc/degs [50176] i32 each    602,112
#define OFF_CI    ((size_t)26733184)     // [196][BCI] i32                 9,408,000
#define OFF_ZERO  ((size_t)36141184)     // 34,624
#define OFF_T     ((size_t)36175808)     // fp8 table [N+1][128]           6,400,128
// zero region internal offsets (bytes)
#define ZO_GCUR 0        // [2][196] i32 bucket counters (1568 B, pad 1600)
#define ZO_SUM  1600     // [G][D] f32 (32768 B)
#define ZO_CNT  34368    // [G] i32 (256 B)
#define ZERO_BYTES 34624

static __device__ __forceinline__ ushort f2b(float f) {
  uint u = __float_as_uint(f);
  uint r = (u + 0x7fffu + ((u >> 16) & 1u)) >> 16;
  return (ushort)r;
}
static __device__ __forceinline__ float blo(uint u) { return __uint_as_float(u << 16); }
static __device__ __forceinline__ float bhi(uint u) { return __uint_as_float(u & 0xffff0000u); }

// ---------------- W prep: fp32 W[l][r][k][n] -> bf16 Ws[l][n][r*128+k] (stacked-K) ----------------
__global__ __launch_bounds__(256) void k_wprep(const float* __restrict__ W,
                                               ushort* __restrict__ WT) {
  int idx = blockIdx.x * 256 + threadIdx.x;  // 65536 total
  int lr = idx >> 14;
  int l = lr >> 1, r = lr & 1;
  int rem = idx & 16383;
  int n = rem >> 7, k = rem & 127;
  WT[l * 32768 + n * 256 + r * 128 + k] = f2b(W[lr * 16384 + k * 128 + n]);
}

// ---------------- x -> fp8 table T[N+1][128] (unscaled; row NN = zero) ----------------
__global__ __launch_bounds__(256) void k_xq(const float* __restrict__ x,
                                            uint* __restrict__ T) {
  int idx = blockIdx.x * 256 + threadIdx.x;  // (NN+1)*32 = 1,600,032 uints
  if (idx >= (NN + 1) * 32) return;
  int row = idx >> 5, q = idx & 31;
  uint u = 0;
  if (row < NN) {
    float4 a = ((const float4*)x)[(size_t)row * 32 + q];
    u = __builtin_amdgcn_cvt_pk_fp8_f32(a.x, a.y, 0u, false);
    u = __builtin_amdgcn_cvt_pk_fp8_f32(a.z, a.w, u, true);
  }
  T[idx] = u;
}

// ---------------- phase 1: partition edges into dst buckets (coalesced) ----------------
__global__ __launch_bounds__(256) void k_part(const int* __restrict__ EI,
                                              int* __restrict__ gcur,
                                              uint* __restrict__ bdata) {
  __shared__ int hist[256];
  __shared__ int sbase[256];
  __shared__ int gbase[256];
  __shared__ int lcur[256];
  __shared__ uint stage[4096];
  __shared__ unsigned char bstage[4096];
  const int r = blockIdx.y;
  const int t = threadIdx.x;
  const int e0 = blockIdx.x * 4096;
  const int cnt = min(4096, EE - e0);
  hist[t] = 0;
  lcur[t] = 0;
  __syncthreads();

  int src[16], dst[16];
  bool val[4];
#pragma unroll
  for (int j = 0; j < 4; ++j) {
    int i4 = (j * 256 + t) * 4;
    val[j] = (i4 < cnt);
    if (val[j]) {
      int4 s4 = *(const int4*)(EI + (size_t)r * 2 * EE + e0 + i4);
      int4 d4 = *(const int4*)(EI + (size_t)r * 2 * EE + EE + e0 + i4);
      src[j * 4 + 0] = s4.x; src[j * 4 + 1] = s4.y; src[j * 4 + 2] = s4.z; src[j * 4 + 3] = s4.w;
      dst[j * 4 + 0] = d4.x; dst[j * 4 + 1] = d4.y; dst[j * 4 + 2] = d4.z; dst[j * 4 + 3] = d4.w;
#pragma unroll
      for (int i = 0; i < 4; ++i) atomicAdd(&hist[dst[j * 4 + i] >> 8], 1);
    }
  }
  __syncthreads();
  int hv = hist[t];
  if (t < NBUK && hv > 0)
    gbase[t] = atomicAdd(&gcur[r * NBUK + t], hv);
  else
    gbase[t] = 0;
  sbase[t] = hv;
  __syncthreads();
  for (int off = 1; off < 256; off <<= 1) {
    int u = (t >= off) ? sbase[t - off] : 0;
    __syncthreads();
    sbase[t] += u;
    __syncthreads();
  }
  int incl = sbase[t];
  hist[t] = incl - hv;
  __syncthreads();
#pragma unroll
  for (int j = 0; j < 4; ++j) {
    if (val[j]) {
#pragma unroll
      for (int i = 0; i < 4; ++i) {
        int d = dst[j * 4 + i];
        int b = d >> 8;
        int p = atomicAdd(&lcur[b], 1);
        int pos = hist[b] + p;
        stage[pos] = ((uint)src[j * 4 + i] << 8) | (uint)(d & 255);
        bstage[pos] = (unsigned char)b;
      }
    }
  }
  __syncthreads();
  for (int s = t; s < cnt; s += 256) {
    int b = (int)bstage[s];
    bdata[(size_t)(r * NBUK + b) * BCAP + gbase[b] + (s - hist[b])] = stage[s];
  }
}

// ---------------- phase 2a: degrees -> isd, rps, rpc, degs ----------------
__global__ __launch_bounds__(256) void k_csr1(const uint* __restrict__ bdata,
                                              const int* __restrict__ gcur,
                                              float* __restrict__ isd,
                                              int* __restrict__ rps,
                                              int* __restrict__ rpc,
                                              int* __restrict__ degs) {
  __shared__ int lcnt0[256], lcnt1[256], lrp[256];
  const int b = blockIdx.x;
  const int t = threadIdx.x;
  const int cnt0 = gcur[b];
  const int cnt1 = gcur[NBUK + b];
  const uint* bd0 = bdata + (size_t)b * BCAP;
  const uint* bd1 = bdata + (size_t)(NBUK + b) * BCAP;
  lcnt0[t] = 0; lcnt1[t] = 0;
  __syncthreads();
  for (int s = t; s < cnt0; s += 256) atomicAdd(&lcnt0[bd0[s] & 255u], 1);
  for (int s = t; s < cnt1; s += 256) atomicAdd(&lcnt1[bd1[s] & 255u], 1);
  __syncthreads();
  const int deg0 = lcnt0[t];
  const int deg1 = lcnt1[t];
  const int node = b * 256 + t;
  const int valid = (node < NN) ? 1 : 0;
  const int ng0 = valid ? ((deg0 + 8) >> 3) : 0;   // ceil((deg0+1)/8)
  const int ng1 = valid ? ((deg1 + 8) >> 3) : 0;
  const int sz = (ng0 + ng1) << 3;
  lrp[t] = sz;
  __syncthreads();
  for (int off = 1; off < 256; off <<= 1) {
    int u = (t >= off) ? lrp[t - off] : 0;
    __syncthreads();
    lrp[t] += u;
    __syncthreads();
  }
  const int ex = lrp[t] - sz;
  rps[node] = b * BCI + ex;
  rpc[node] = ng0 | (ng1 << 16);
  degs[node] = deg0 | (deg1 << 16);
  if (valid) {
    isd[node] = rsqrtf((float)(deg0 + 1));
    isd[NN + node] = rsqrtf((float)(deg1 + 1));
  }
}

// ---------------- phase 2b: scatter edges -> ci entries (src16 | bf16(isd_r[src]*isd_r[dst])<<16) ----------------
// The dst-side factor is FOLDED into the per-edge scale (self: isd^2, pads: scale 0),
// so k_agg needs no isd reads and a single accumulator set per relation sub-loop.
__global__ __launch_bounds__(256) void k_csr2(const uint* __restrict__ bdata,
                                              const int* __restrict__ gcur,
                                              const float* __restrict__ isd,
                                              const int* __restrict__ rps,
                                              const int* __restrict__ rpc,
                                              const int* __restrict__ degs,
                                              int* __restrict__ ci) {
  __shared__ int lex[256], lb1[256], lcurA[256], lcurB[256];
  __shared__ float lisd0[256], lisd1[256];
  __shared__ int cstage[BCI];   // 48,000 B + ~6 KB = 54 KB
  __shared__ int shtot;
  const int b = blockIdx.x;
  const int t = threadIdx.x;
  const int node = b * 256 + t;
  const int cnt0 = gcur[b];
  const int cnt1 = gcur[NBUK + b];
  const uint* bd0 = bdata + (size_t)b * BCAP;
  const uint* bd1 = bdata + (size_t)(NBUK + b) * BCAP;
  const int ex = rps[node] - b * BCI;
  const int meta = rpc[node];
  const int ng0 = meta & 0xffff, ng1 = (meta >> 16) & 0xffff;
  const int dg = degs[node];
  const int deg0 = dg & 0xffff, deg1 = (dg >> 16) & 0xffff;
  const int valid = (node < NN) ? 1 : 0;
  lex[t] = ex;
  lb1[t] = ng0 << 3;
  lcurA[t] = 0;
  lcurB[t] = 0;
  lisd0[t] = valid ? isd[node] : 0.f;
  lisd1[t] = valid ? isd[NN + node] : 0.f;
  if (t == 255) shtot = ex + ((ng0 + ng1) << 3);
  __syncthreads();
  const int tot = shtot;
  if (t < 32) cstage[tot + t] = NN;   // tail pads (scale 0) for k_agg over-read
  if (valid) {
    const float d0 = lisd0[t], d1 = lisd1[t];
    cstage[ex + deg0] = node | ((uint)f2b(d0 * d0) << 16);      // r0 self
    for (int p = deg0 + 1; p < (ng0 << 3); ++p) cstage[ex + p] = NN;
    const int e1 = ex + (ng0 << 3);
    cstage[e1 + deg1] = node | ((uint)f2b(d1 * d1) << 16);      // r1 self
    for (int p = deg1 + 1; p < (ng1 << 3); ++p) cstage[e1 + p] = NN;
  }
  // scatter real edges (disjoint slots vs selfs/pads)
  for (int s = t; s < cnt0; s += 256) {
    uint pr = bd0[s];
    int j = (int)(pr & 255u);
    int sr = (int)(pr >> 8);
    int p = atomicAdd(&lcurA[j], 1);
    cstage[lex[j] + p] = sr | ((uint)f2b(isd[sr] * lisd0[j]) << 16);
  }
  for (int s = t; s < cnt1; s += 256) {
    uint pr = bd1[s];
    int j = (int)(pr & 255u);
    int sr = (int)(pr >> 8);
    int p = atomicAdd(&lcurB[j], 1);
    cstage[lex[j] + lb1[j] + p] = sr | ((uint)f2b(isd[NN + sr] * lisd1[j]) << 16);
  }
  __syncthreads();
  int* co = ci + (size_t)b * BCI;
  const int on = tot + 32;
  for (int s = t; s < on; s += 256) co[s] = cstage[s];
}

// ---------------- aggregation: 1 wave/node, depth-3 pipeline spanning both relations ----------------
// lane = g*8 + c: g = edge slot (0..7), c = channel-quad (16 fp8 ch = 1 uint4).
// Scales are fully folded per-edge, so a SINGLE acc[8] set is live; after the r0
// sub-loop we reduce+write half 0, zero acc, and the pipeline continues into r1
// without a refill. Prefetch indices clamped to the zero row NN.
#define AGG_STEP()                                                             \
  {                                                                            \
    uint e3 = (uint)ce[ip];                                                    \
    int s3 = (ip < lim) ? (int)(e3 & 0xffffu) : NN;                            \
    float f3 = bhi(e3);                                                        \
    ip += 8;                                                                   \
    uint4 d3 = *(const uint4*)(Tb + ((((size_t)(uint)s3) << 7) + cb));         \
    f32x2 sc; sc[0] = f0; sc[1] = f0;                                          \
    f32x2 v;                                                                   \
    v = __builtin_amdgcn_cvt_pk_f32_fp8(d0.x, false); acc[0] += v * sc;        \
    v = __builtin_amdgcn_cvt_pk_f32_fp8(d0.x, true);  acc[1] += v * sc;        \
    v = __builtin_amdgcn_cvt_pk_f32_fp8(d0.y, false); acc[2] += v * sc;        \
    v = __builtin_amdgcn_cvt_pk_f32_fp8(d0.y, true);  acc[3] += v * sc;        \
    v = __builtin_amdgcn_cvt_pk_f32_fp8(d0.z, false); acc[4] += v * sc;        \
    v = __builtin_amdgcn_cvt_pk_f32_fp8(d0.z, true);  acc[5] += v * sc;        \
    v = __builtin_amdgcn_cvt_pk_f32_fp8(d0.w, false); acc[6] += v * sc;        \
    v = __builtin_amdgcn_cvt_pk_f32_fp8(d0.w, true);  acc[7] += v * sc;        \
    d0 = d1; d1 = d2; d2 = d3; f0 = f1; f1 = f2; f2 = f3;                      \
  }

#define AGG_REDUCE_WRITE(halfoff)                                              \
  {                                                                            \
    _Pragma("unroll")                                                          \
    for (int mask = 8; mask <= 32; mask <<= 1) {                               \
      _Pragma("unroll")                                                        \
      for (int j = 0; j < 8; ++j) {                                            \
        f32x2 o;                                                               \
        o[0] = __shfl_xor(acc[j][0], mask);                                    \
        o[1] = __shfl_xor(acc[j][1], mask);                                    \
        acc[j] += o;                                                           \
      }                                                                        \
    }                                                                          \
    if (g == 0 && node < NN) {                                                 \
      ushort* row = aggo + (size_t)node * 256 + (halfoff);                     \
      uint pk[8];                                                              \
      _Pragma("unroll")                                                        \
      for (int j = 0; j < 8; ++j)                                              \
        pk[j] = (uint)f2b(acc[j][0]) | ((uint)f2b(acc[j][1]) << 16);           \
      *(uint4*)(row + c * 16) = make_uint4(pk[0], pk[1], pk[2], pk[3]);        \
      *(uint4*)(row + c * 16 + 8) = make_uint4(pk[4], pk[5], pk[6], pk[7]);    \
    }                                                                          \
  }

__global__ __launch_bounds__(256) void k_agg(const char* __restrict__ Tb,
                                             const int* __restrict__ rps,
                                             const int* __restrict__ rpc,
                                             const int* __restrict__ ci,
                                             ushort* __restrict__ aggo) {
  const int w = threadIdx.x >> 6;
  const int lane = threadIdx.x & 63;
  const int g = lane >> 3, c = lane & 7;
  const int node = blockIdx.x * 4 + w;   // 0..50175
  const size_t cb = (size_t)c * 16;

  const int meta = rpc[node];
  const int ng0 = meta & 0xffff;
  const int ng1 = (meta >> 16) & 0xffff;
  const int lim = (ng0 + ng1) << 3;
  const int* ce = ci + rps[node];

  // pipeline fill: depth-3 data, scales carried alongside
  int ip = g;
  uint e0 = (uint)ce[ip];
  int s0 = (ip < lim) ? (int)(e0 & 0xffffu) : NN;
  float f0 = bhi(e0);
  ip += 8;
  uint4 d0 = *(const uint4*)(Tb + ((((size_t)(uint)s0) << 7) + cb));
  uint e1 = (uint)ce[ip];
  int s1 = (ip < lim) ? (int)(e1 & 0xffffu) : NN;
  float f1 = bhi(e1);
  ip += 8;
  uint4 d1 = *(const uint4*)(Tb + ((((size_t)(uint)s1) << 7) + cb));
  uint e2 = (uint)ce[ip];
  int s2 = (ip < lim) ? (int)(e2 & 0xffffu) : NN;
  float f2 = bhi(e2);
  ip += 8;
  uint4 d2 = *(const uint4*)(Tb + ((((size_t)(uint)s2) << 7) + cb));

  f32x2 acc[8];
#pragma unroll
  for (int j = 0; j < 8; ++j) { acc[j][0] = 0.f; acc[j][1] = 0.f; }

  for (int q = 0; q < ng0; ++q) AGG_STEP();
  AGG_REDUCE_WRITE(0);
#pragma unroll
  for (int j = 0; j < 8; ++j) { acc[j][0] = 0.f; acc[j][1] = 0.f; }
  for (int q = 0; q < ng1; ++q) AGG_STEP();
  AGG_REDUCE_WRITE(128);
}

// ---------------- MFMA GEMM: out[m][:] = agg[m][0:256] @ Ws[l] + bsum, K=256, BM=64 ----------------
#define AL_S 72
#define WT_S 72
template <int OUT>
__global__ __launch_bounds__(256) void k_gemm(const ushort* __restrict__ A,
                                              const ushort* __restrict__ WTg,
                                              const float* __restrict__ bias,
                                              uint* __restrict__ Yfp8,
                                              ushort* __restrict__ Ybf) {
  __shared__ ushort WTl[128 * WT_S];
  __shared__ ushort Al[64 * AL_S];
  const int m0b = blockIdx.x * 64;
  const int t = threadIdx.x;
  const int w = t >> 6, L = t & 63, q = L >> 4, ln = L & 15;

  f32x4 acc[8];
#pragma unroll
  for (int nt = 0; nt < 8; ++nt) {
    acc[nt][0] = 0.f; acc[nt][1] = 0.f; acc[nt][2] = 0.f; acc[nt][3] = 0.f;
  }

  for (int hh = 0; hh < 4; ++hh) {
    __syncthreads();
    {
      int n = t >> 1, half = t & 1;
#pragma unroll
      for (int j = 0; j < 4; ++j)
        *(uint4*)(&WTl[n * WT_S + half * 32 + j * 8]) =
            *(const uint4*)(WTg + n * 256 + hh * 64 + half * 32 + j * 8);
      int row = t >> 2, seg = t & 3;
      int gm = m0b + row;
      if (gm < NN) {
#pragma unroll
        for (int j = 0; j < 2; ++j)
          *(uint4*)(&Al[row * AL_S + seg * 16 + j * 8]) =
              *(const uint4*)(A + (size_t)gm * 256 + hh * 64 + seg * 16 + j * 8);
      } else {
        uint4 z = make_uint4(0, 0, 0, 0);
#pragma unroll
        for (int j = 0; j < 2; ++j) *(uint4*)(&Al[row * AL_S + seg * 16 + j * 8]) = z;
      }
    }
    __syncthreads();
#pragma unroll
    for (int kk = 0; kk < 2; ++kk) {
      bf16x8 bfr = *(const bf16x8*)(&Al[(w * 16 + ln) * AL_S + kk * 32 + q * 8]);
#pragma unroll
      for (int nt = 0; nt < 8; ++nt) {
        bf16x8 a = *(const bf16x8*)(&WTl[(nt * 16 + ln) * WT_S + kk * 32 + q * 8]);
        acc[nt] = __builtin_amdgcn_mfma_f32_16x16x32_bf16(a, bfr, acc[nt], 0, 0, 0);
      }
    }
  }
  const int m = m0b + w * 16 + ln;
  if (OUT == 0) {
    if (m < NN) {
      uint* yp = Yfp8 + (size_t)m * 32;
#pragma unroll
      for (int nt = 0; nt < 8; ++nt) {
        int n0 = nt * 16 + q * 4;
        float4 bL = *(const float4*)(bias + n0);
        float4 bH = *(const float4*)(bias + 128 + n0);
        f32x4 v = acc[nt];
        float o0 = fmaxf(v[0] + bL.x + bH.x, 0.f);
        float o1 = fmaxf(v[1] + bL.y + bH.y, 0.f);
        float o2 = fmaxf(v[2] + bL.z + bH.z, 0.f);
        float o3 = fmaxf(v[3] + bL.w + bH.w, 0.f);
        uint u = __builtin_amdgcn_cvt_pk_fp8_f32(o0, o1, 0u, false);
        u = __builtin_amdgcn_cvt_pk_fp8_f32(o2, o3, u, true);
        yp[nt * 4 + q] = u;
      }
    } else if (m == NN) {
      uint* yp = Yfp8 + (size_t)m * 32;
#pragma unroll
      for (int nt = 0; nt < 8; ++nt) yp[nt * 4 + q] = 0u;
    }
  } else {
    if (m < NN) {
      uint* yp = (uint*)(Ybf + (size_t)m * 256);
#pragma unroll
      for (int nt = 0; nt < 8; ++nt) {
        int n0 = nt * 16 + q * 4;
        float4 bL = *(const float4*)(bias + n0);
        float4 bH = *(const float4*)(bias + 128 + n0);
        f32x4 v = acc[nt];
        float o0 = v[0] + bL.x + bH.x;
        float o1 = v[1] + bL.y + bH.y;
        float o2 = v[2] + bL.z + bH.z;
        float o3 = v[3] + bL.w + bH.w;
        yp[nt * 8 + q * 2] = (uint)f2b(o0) | ((uint)f2b(o1) << 16);
        yp[nt * 8 + q * 2 + 1] = (uint)f2b(o2) | ((uint)f2b(o3) << 16);
      }
    }
  }
}

// ---------------- pooling (batch ids sorted); h packed bf16 in agg rows, stride 128 uints ----------------
#define PCHUNK 32
__global__ __launch_bounds__(64) void k_pool(const uint* __restrict__ h,
                                             const int* __restrict__ batch,
                                             float* __restrict__ sums,
                                             int* __restrict__ counts) {
  int lane = threadIdx.x;
  int n0 = blockIdx.x * PCHUNK;
  int n1 = n0 + PCHUNK;
  if (n1 > NN) n1 = NN;
  if (n0 >= NN) return;
  float aLo = 0.f, aHi = 0.f;
  int cnt = 0;
  int g = batch[n0];
  uint u = h[(size_t)n0 * 128 + lane];
  for (int n = n0; n < n1; ++n) {
    uint unext = 0;
    int gnext = g;
    if (n + 1 < n1) {
      unext = h[(size_t)(n + 1) * 128 + lane];
      gnext = batch[n + 1];
    }
    aLo += blo(u);
    aHi += bhi(u);
    cnt++;
    if (n + 1 < n1 && gnext != g) {
      atomicAdd(&sums[g * DD + lane * 2], aLo);
      atomicAdd(&sums[g * DD + lane * 2 + 1], aHi);
      if (lane == 0) atomicAdd(&counts[g], cnt);
      aLo = 0.f; aHi = 0.f; cnt = 0;
      g = gnext;
    }
    u = unext;
  }
  atomicAdd(&sums[g * DD + lane * 2], aLo);
  atomicAdd(&sums[g * DD + lane * 2 + 1], aHi);
  if (lane == 0) atomicAdd(&counts[g], cnt);
}

__global__ __launch_bounds__(512) void k_final(const float* __restrict__ sums,
                                               const int* __restrict__ counts,
                                               const float* __restrict__ lin_w,
                                               const float* __restrict__ lin_b,
                                               float* __restrict__ out) {
  int t = threadIdx.x;  // 512 = 64 graphs x 8 classes
  int g = t >> 3, co = t & 7;
  float cnt = (float)counts[g];
  if (cnt < 1.f) cnt = 1.f;
  float inv = 1.f / cnt;
  float v = lin_b[co];
  for (int d = 0; d < DD; ++d) v += (sums[g * DD + d] * inv) * lin_w[d * CCLS + co];
  out[t] = v;
}

extern "C" void kernel_launch(void* const* d_in, const int* in_sizes, int n_in,
                              void* d_out, int out_size, void* d_ws, size_t ws_size,
                              hipStream_t stream) {
  (void)in_sizes; (void)n_in; (void)out_size; (void)ws_size;
  const float* x     = (const float*)d_in[0];
  const float* W     = (const float*)d_in[1];
  const float* b     = (const float*)d_in[2];
  const float* lin_w = (const float*)d_in[3];
  const float* lin_b = (const float*)d_in[4];
  const int*   EI    = (const int*)d_in[5];
  const int*   batch = (const int*)d_in[6];
  float* out = (float*)d_out;

  char* ws = (char*)d_ws;
  ushort* agg   = (ushort*)(ws + OFF_AGG);
  uint*   bdata = (uint*)(ws + OFF_AGG);      // ALIAS: dead after k_csr2
  ushort* Ws    = (ushort*)(ws + OFF_WBT);
  float*  isd   = (float*)(ws + OFF_ISD);
  int*    rps   = (int*)(ws + OFF_RP);
  int*    rpc   = rps + NBUK * 256;
  int*    degs  = rpc + NBUK * 256;
  int*    ci    = (int*)(ws + OFF_CI);
  uint*   T     = (uint*)(ws + OFF_T);
  char*   zb    = ws + OFF_ZERO;
  int*    gcur  = (int*)(zb + ZO_GCUR);
  float*  sums  = (float*)(zb + ZO_SUM);
  int*    counts= (int*)(zb + ZO_CNT);

  (void)hipMemsetAsync(zb, 0, ZERO_BYTES, stream);

  k_wprep<<<256, 256, 0, stream>>>(W, Ws);
  k_xq<<<((NN + 1) * 32 + 255) / 256, 256, 0, stream>>>(x, T);
  k_part<<<dim3((EE + 4095) / 4096, RR), 256, 0, stream>>>(EI, gcur, bdata);
  k_csr1<<<NBUK, 256, 0, stream>>>(bdata, gcur, isd, rps, rpc, degs);
  k_csr2<<<NBUK, 256, 0, stream>>>(bdata, gcur, isd, rps, rpc, degs, ci);

  const int gagg = NBUK * 256 / 4;
  const int ggemm = (NN + 63) / 64;
  // layer 0: aggregate fp8(x), GEMM K=256 -> relu -> fp8 table T (in place over T0)
  k_agg<<<gagg, 256, 0, stream>>>((const char*)T, rps, rpc, ci, agg);
  k_gemm<0><<<ggemm, 256, 0, stream>>>(agg, Ws, b, T, nullptr);
  // layer 1: aggregate T1, GEMM K=256 -> packed bf16 h in place in agg rows
  k_agg<<<gagg, 256, 0, stream>>>((const char*)T, rps, rpc, ci, agg);
  k_gemm<1><<<ggemm, 256, 0, stream>>>(agg, Ws + 32768, b + 256, nullptr, agg);

  k_pool<<<(NN + PCHUNK - 1) / PCHUNK, 64, 0, stream>>>((const uint*)agg, batch, sums, counts);
  k_final<<<1, GG * CCLS, 0, stream>>>(sums, counts, lin_w, lin_b, out);
}

// Round 8
// 287.480 us; speedup vs baseline: 1.0403x; 1.0403x over previous
//
#include <hip/hip_runtime.h>
#include <math.h>

#define NN 50000
#define EE 800000
#define RR 2
#define LL 2
#define DD 128
#define GG 64
#define CCLS 8
#define NBUK 196     // buckets of 256 dst nodes: bucket = dst >> 8
#define NPAD 50176   // NBUK*256 (padded node count for rps/rpc arrays)
#define BCAP 6144    // max raw edges per bucket per relation (mean 4082, sigma 64)
#define BCI  8256    // per-bucket per-relation CSR slots: <=6144 edges + 256 selfs
                     // + pads to %8 (worst 6144+2048=8192) + 16 tail <= 8208 < 8256

typedef unsigned int uint;
typedef unsigned short ushort;
typedef short bf16x8 __attribute__((ext_vector_type(8)));
typedef float f32x4 __attribute__((ext_vector_type(4)));
typedef float f32x2 __attribute__((ext_vector_type(2)));

// ---------------- workspace layout (bytes), peak 39,914,176 ----------------
#define OFF_H1    ((size_t)0)            // [N][64] uint packed bf16      12,800,000
#define OFF_WBT   ((size_t)12800000)     // [L][R][128][128] bf16            131,072
#define OFF_ISD   ((size_t)12931072)     // [2][N] f32                       400,000
#define OFF_RP    ((size_t)13331072)     // rps[2][NPAD]+rpc[2][NPAD] i32    802,816
#define OFF_CI    ((size_t)14133888)     // [2][196][BCI] i32             12,945,408
#define OFF_ZERO  ((size_t)27079296)     // 34,624
#define OFF_BD    ((size_t)27113920)     // [2][196][BCAP] uint            9,633,792
#define OFF_XW    ((size_t)27113920)     // ALIAS of BD (bdata dead after k_csr):
                                         // [2][N+1][128] fp8             12,800,256
// zero region internal offsets (bytes)
#define ZO_GCUR 0        // [2][196] i32 bucket counters (1568 B, pad 1600)
#define ZO_SUM  1600     // [G][D] f32 (32768 B)
#define ZO_CNT  34368    // [G] i32 (256 B)
#define ZERO_BYTES 34624

static __device__ __forceinline__ ushort f2b(float f) {
  uint u = __float_as_uint(f);
  uint r = (u + 0x7fffu + ((u >> 16) & 1u)) >> 16;
  return (ushort)r;
}
static __device__ __forceinline__ float blo(uint u) { return __uint_as_float(u << 16); }
static __device__ __forceinline__ float bhi(uint u) { return __uint_as_float(u & 0xffff0000u); }

// ---------------- W prep: fp32 W[l][r][k][n] -> bf16 WbfT[l][r][n][k] ----------------
__global__ __launch_bounds__(256) void k_wprep(const float* __restrict__ W,
                                               ushort* __restrict__ WT) {
  int idx = blockIdx.x * 256 + threadIdx.x;  // 65536 total
  int lr = idx >> 14;
  int rem = idx & 16383;
  int n = rem >> 7, k = rem & 127;
  WT[lr * 16384 + n * 128 + k] = f2b(W[lr * 16384 + k * 128 + n]);
}

// ---------------- phase 1: partition edges into dst buckets (coalesced) ----------------
__global__ __launch_bounds__(256) void k_part(const int* __restrict__ EI,
                                              int* __restrict__ gcur,
                                              uint* __restrict__ bdata) {
  __shared__ int hist[256];
  __shared__ int sbase[256];
  __shared__ int gbase[256];
  __shared__ int lcur[256];
  __shared__ uint stage[4096];
  __shared__ unsigned char bstage[4096];
  const int r = blockIdx.y;
  const int t = threadIdx.x;
  const int e0 = blockIdx.x * 4096;
  const int cnt = min(4096, EE - e0);
  hist[t] = 0;
  lcur[t] = 0;
  __syncthreads();

  int src[16], dst[16];
  bool val[4];
#pragma unroll
  for (int j = 0; j < 4; ++j) {
    int i4 = (j * 256 + t) * 4;
    val[j] = (i4 < cnt);
    if (val[j]) {
      int4 s4 = *(const int4*)(EI + (size_t)r * 2 * EE + e0 + i4);
      int4 d4 = *(const int4*)(EI + (size_t)r * 2 * EE + EE + e0 + i4);
      src[j * 4 + 0] = s4.x; src[j * 4 + 1] = s4.y; src[j * 4 + 2] = s4.z; src[j * 4 + 3] = s4.w;
      dst[j * 4 + 0] = d4.x; dst[j * 4 + 1] = d4.y; dst[j * 4 + 2] = d4.z; dst[j * 4 + 3] = d4.w;
#pragma unroll
      for (int i = 0; i < 4; ++i) atomicAdd(&hist[dst[j * 4 + i] >> 8], 1);
    }
  }
  __syncthreads();
  int hv = hist[t];
  if (t < NBUK && hv > 0)
    gbase[t] = atomicAdd(&gcur[r * NBUK + t], hv);
  else
    gbase[t] = 0;
  sbase[t] = hv;
  __syncthreads();
  for (int off = 1; off < 256; off <<= 1) {
    int u = (t >= off) ? sbase[t - off] : 0;
    __syncthreads();
    sbase[t] += u;
    __syncthreads();
  }
  int incl = sbase[t];
  hist[t] = incl - hv;  // exclusive stage offset
  __syncthreads();
#pragma unroll
  for (int j = 0; j < 4; ++j) {
    if (val[j]) {
#pragma unroll
      for (int i = 0; i < 4; ++i) {
        int d = dst[j * 4 + i];
        int b = d >> 8;
        int p = atomicAdd(&lcur[b], 1);
        int pos = hist[b] + p;
        stage[pos] = ((uint)src[j * 4 + i] << 8) | (uint)(d & 255);
        bstage[pos] = (unsigned char)b;
      }
    }
  }
  __syncthreads();
  for (int s = t; s < cnt; s += 256) {
    int b = (int)bstage[s];
    bdata[(size_t)(r * NBUK + b) * BCAP + gbase[b] + (s - hist[b])] = stage[s];
  }
}

// ---------------- phase 2: per-relation padded CSR ----------------
// Per node per relation: [deg edges..., self(node), pads(NN) to %8]. Row NN of the
// fp8 table is zero, so pad slots add 0 with NO branch in k_agg's steady loop.
__global__ __launch_bounds__(256) void k_csr(const uint* __restrict__ bdata,
                                             const int* __restrict__ gcur,
                                             float* __restrict__ isd,
                                             int* __restrict__ rps,
                                             int* __restrict__ rpc,
                                             int* __restrict__ ci) {
  __shared__ int lcnt[256], lrp[256], lex[256], lcur[256];
  __shared__ int cstage[BCI];   // 33,024 B + 4 KB arrays = 37 KB
  __shared__ int shtot;
  const int b = blockIdx.x;
  const int r = blockIdx.y;
  const int t = threadIdx.x;
  const int cnt = gcur[r * NBUK + b];
  const uint* bd = bdata + (size_t)(r * NBUK + b) * BCAP;
  lcnt[t] = 0;
  lcur[t] = 0;
  __syncthreads();
  for (int s = t; s < cnt; s += 256) atomicAdd(&lcnt[bd[s] & 255u], 1);
  __syncthreads();
  const int deg = lcnt[t];
  const int node = b * 256 + t;
  const int valid = (node < NN) ? 1 : 0;
  const int ng = valid ? ((deg + 8) >> 3) : 0;   // ceil((deg+1)/8)
  const int sz = ng << 3;
  lrp[t] = sz;
  __syncthreads();
  for (int off = 1; off < 256; off <<= 1) {
    int u = (t >= off) ? lrp[t - off] : 0;
    __syncthreads();
    lrp[t] += u;
    __syncthreads();
  }
  const int incl = lrp[t];
  if (t == 255) shtot = incl;
  lex[t] = incl - sz;
  __syncthreads();   // publish lex / shtot
  const int ex = lex[t];
  const int btot = shtot;
  rps[r * NPAD + node] = b * BCI + ex;
  rpc[r * NPAD + node] = ng;
  if (t < 16) cstage[btot + t] = NN;   // tail pads for k_agg index over-read
  if (valid) {
    isd[r * NN + node] = rsqrtf((float)(deg + 1));
    cstage[ex + deg] = node;                         // self edge
    for (int p = deg + 1; p < sz; ++p) cstage[ex + p] = NN;  // zero-row pads
  }
  // scatter real edges (disjoint slots vs selfs/pads)
  for (int s = t; s < cnt; s += 256) {
    uint pr = bd[s];
    int j = (int)(pr & 255u);
    int p = atomicAdd(&lcur[j], 1);
    cstage[lex[j] + p] = (int)(pr >> 8);
  }
  __syncthreads();
  int* co = ci + (size_t)(r * NBUK + b) * BCI;
  const int on = btot + 16;
  for (int s = t; s < on; s += 256) co[s] = cstage[s];
}

// ---------------- MFMA GEMM: xw'[r][m][:] = (X[m][:] @ W[r]) * isd[r][m], fp8 out ----------------
#define AL_S 72    // 64+8 bf16 row stride
#define WT_S 136   // 128+8 bf16 row stride
template <int IN_BF16>
__global__ __launch_bounds__(256) void k_gemm(const void* __restrict__ Xv,
                                              const ushort* __restrict__ WTg,
                                              const float* __restrict__ isd,
                                              uint* __restrict__ Y) {
  __shared__ ushort WTl[128 * WT_S];
  __shared__ ushort Al[128 * AL_S];
  const int r = blockIdx.y;
  const int m0b = blockIdx.x * 128;
  const int t = threadIdx.x;
  const int w = t >> 6, L = t & 63, q = L >> 4, ln = L & 15;
  uint* Yr = Y + (size_t)r * (NN + 1) * 32;   // fp8 row = 32 uints, +1 zero row
  const ushort* WTr = WTg + (size_t)r * 16384;

#pragma unroll
  for (int i = 0; i < 8; ++i) {
    int g = t + i * 256;
    int n = g >> 4, k0 = (g & 15) * 8;
    *(uint4*)(&WTl[n * WT_S + k0]) = *(const uint4*)(WTr + n * 128 + k0);
  }

  f32x4 acc[2][8];
#pragma unroll
  for (int mt = 0; mt < 2; ++mt)
#pragma unroll
    for (int nt = 0; nt < 8; ++nt) {
      acc[mt][nt][0] = 0.f; acc[mt][nt][1] = 0.f;
      acc[mt][nt][2] = 0.f; acc[mt][nt][3] = 0.f;
    }

  for (int hh = 0; hh < 2; ++hh) {
    __syncthreads();
    {
      int row = t >> 1, ch = t & 1;
      int gm = m0b + row;
      ushort* dst = &Al[row * AL_S + ch * 32];
      if (gm < NN) {
        if (IN_BF16) {
          const uint4* xp = (const uint4*)((const ushort*)Xv + (size_t)gm * 128 + hh * 64 + ch * 32);
#pragma unroll
          for (int j = 0; j < 4; ++j) ((uint4*)dst)[j] = xp[j];
        } else {
          const float4* xp = (const float4*)((const float*)Xv + (size_t)gm * 128 + hh * 64 + ch * 32);
          ushort tmp[32];
#pragma unroll
          for (int j = 0; j < 8; ++j) {
            float4 v = xp[j];
            tmp[j * 4 + 0] = f2b(v.x); tmp[j * 4 + 1] = f2b(v.y);
            tmp[j * 4 + 2] = f2b(v.z); tmp[j * 4 + 3] = f2b(v.w);
          }
#pragma unroll
          for (int j = 0; j < 4; ++j) ((uint4*)dst)[j] = ((uint4*)tmp)[j];
        }
      } else {
        uint4 z = make_uint4(0, 0, 0, 0);
#pragma unroll
        for (int j = 0; j < 4; ++j) ((uint4*)dst)[j] = z;
      }
    }
    __syncthreads();
#pragma unroll
    for (int kk = 0; kk < 2; ++kk) {
      bf16x8 b0 = *(const bf16x8*)(&Al[(w * 32 + ln) * AL_S + kk * 32 + q * 8]);
      bf16x8 b1 = *(const bf16x8*)(&Al[(w * 32 + 16 + ln) * AL_S + kk * 32 + q * 8]);
#pragma unroll
      for (int nt = 0; nt < 8; ++nt) {
        bf16x8 a = *(const bf16x8*)(&WTl[(nt * 16 + ln) * WT_S + hh * 64 + kk * 32 + q * 8]);
        acc[0][nt] = __builtin_amdgcn_mfma_f32_16x16x32_bf16(a, b0, acc[0][nt], 0, 0, 0);
        acc[1][nt] = __builtin_amdgcn_mfma_f32_16x16x32_bf16(a, b1, acc[1][nt], 0, 0, 0);
      }
    }
  }
  // epilogue: lane holds D for m = m0b + w*32 + mt*16 + ln, n = nt*16 + q*4 + reg
  // m == NN is the zero row used by k_agg's pad slots (acc==0 there since Al was zeroed).
#pragma unroll
  for (int mt = 0; mt < 2; ++mt) {
    int m = m0b + w * 32 + mt * 16 + ln;
    if (m <= NN) {
      float sc = (m < NN) ? isd[r * NN + m] : 0.f;
      uint* yp = Yr + (size_t)m * 32;
#pragma unroll
      for (int nt = 0; nt < 8; ++nt) {
        f32x4 v = acc[mt][nt];
        uint u = __builtin_amdgcn_cvt_pk_fp8_f32(v[0] * sc, v[1] * sc, 0u, false);
        u = __builtin_amdgcn_cvt_pk_fp8_f32(v[2] * sc, v[3] * sc, u, true);
        yp[nt * 4 + q] = u;
      }
    }
  }
}

// ---------------- aggregation: round-0 structure + padded CSR + packed accumulate ----------------
// 1 wave/node; lane = g*8 + c: g = edge slot (0..7), c = channel-quad (16 fp8 ch = uint4).
// Per relation: branch-free steady loop (pads hit the zero row NN), depth-1 data with
// index-ahead prefetch; relations phase-separated (one 6.4 MB table half live at a time);
// SINGLE reduce-epilogue over tot = di0*acc_r0 + di1*acc_r1; 128-ch bf16 output.
__global__ __launch_bounds__(256) void k_agg(const char* __restrict__ xw,
                                             const int* __restrict__ rps,
                                             const int* __restrict__ rpc,
                                             const int* __restrict__ ci,
                                             const float* __restrict__ isd,
                                             const float* __restrict__ bias,
                                             uint* __restrict__ hout, int relu_flag) {
  const int w = threadIdx.x >> 6;
  const int lane = threadIdx.x & 63;
  const int g = lane >> 3, c = lane & 7;
  const int node = blockIdx.x * 4 + w;   // 0..50175
  const size_t cb = (size_t)c * 16;
  const int nsafe = (node < NN) ? node : 0;

  f32x2 tot[8];
#pragma unroll
  for (int j = 0; j < 8; ++j) { tot[j][0] = 0.f; tot[j][1] = 0.f; }

#pragma unroll
  for (int r = 0; r < RR; ++r) {
    const char* xwr = xw + (size_t)r * ((size_t)(NN + 1) * 128);
    const int* ce = ci + (size_t)r * (NBUK * BCI) + rps[r * NPAD + node];
    const int ng = rpc[r * NPAD + node];
    const float di = isd[r * NN + nsafe];

    f32x2 acc[8];
#pragma unroll
    for (int j = 0; j < 8; ++j) { acc[j][0] = 0.f; acc[j][1] = 0.f; }

    int s_cur = ce[g];
    int ip = 8 + g;
    for (int q = 0; q < ng; ++q) {
      int s_next = ce[ip];   // index-ahead (tail pads guarantee readability)
      ip += 8;
      uint4 u = *(const uint4*)(xwr + ((((size_t)(uint)s_cur) << 7) + cb));
      f32x2 v;
      v = __builtin_amdgcn_cvt_pk_f32_fp8(u.x, false); acc[0] += v;
      v = __builtin_amdgcn_cvt_pk_f32_fp8(u.x, true);  acc[1] += v;
      v = __builtin_amdgcn_cvt_pk_f32_fp8(u.y, false); acc[2] += v;
      v = __builtin_amdgcn_cvt_pk_f32_fp8(u.y, true);  acc[3] += v;
      v = __builtin_amdgcn_cvt_pk_f32_fp8(u.z, false); acc[4] += v;
      v = __builtin_amdgcn_cvt_pk_f32_fp8(u.z, true);  acc[5] += v;
      v = __builtin_amdgcn_cvt_pk_f32_fp8(u.w, false); acc[6] += v;
      v = __builtin_amdgcn_cvt_pk_f32_fp8(u.w, true);  acc[7] += v;
      s_cur = s_next;
    }
    f32x2 d2; d2[0] = di; d2[1] = di;
#pragma unroll
    for (int j = 0; j < 8; ++j) tot[j] += acc[j] * d2;
  }

  // single reduce over 8 edge slots (lane bits 3,4,5)
#pragma unroll
  for (int mask = 8; mask <= 32; mask <<= 1) {
#pragma unroll
    for (int j = 0; j < 8; ++j) {
      f32x2 o;
      o[0] = __shfl_xor(tot[j][0], mask);
      o[1] = __shfl_xor(tot[j][1], mask);
      tot[j] += o;
    }
  }

  if (g == 0 && node < NN) {    // lanes 0..7 write channels [c*16, c*16+16)
    const float4* p0 = (const float4*)(bias + c * 16);
    const float4* p1 = (const float4*)(bias + DD + c * 16);
    float o[16];
#pragma unroll
    for (int j = 0; j < 4; ++j) {
      float4 a = p0[j], bq = p1[j];
      o[4 * j + 0] = tot[2 * j][0] + a.x + bq.x;
      o[4 * j + 1] = tot[2 * j][1] + a.y + bq.y;
      o[4 * j + 2] = tot[2 * j + 1][0] + a.z + bq.z;
      o[4 * j + 3] = tot[2 * j + 1][1] + a.w + bq.w;
    }
    if (relu_flag) {
#pragma unroll
      for (int j = 0; j < 16; ++j) o[j] = fmaxf(o[j], 0.f);
    }
    uint pk[8];
#pragma unroll
    for (int j = 0; j < 8; ++j)
      pk[j] = (uint)f2b(o[2 * j]) | ((uint)f2b(o[2 * j + 1]) << 16);
    uint4* dst = (uint4*)(hout + (size_t)node * 64) + c * 2;
    dst[0] = make_uint4(pk[0], pk[1], pk[2], pk[3]);
    dst[1] = make_uint4(pk[4], pk[5], pk[6], pk[7]);
  }
}

// ---------------- pooling (batch ids sorted), packed bf16 input ----------------
#define PCHUNK 32
__global__ __launch_bounds__(64) void k_pool(const uint* __restrict__ h,
                                             const int* __restrict__ batch,
                                             float* __restrict__ sums,
                                             int* __restrict__ counts) {
  int lane = threadIdx.x;
  int n0 = blockIdx.x * PCHUNK;
  int n1 = n0 + PCHUNK;
  if (n1 > NN) n1 = NN;
  if (n0 >= NN) return;
  float aLo = 0.f, aHi = 0.f;
  int cnt = 0;
  int g = batch[n0];
  uint u = h[(size_t)n0 * 64 + lane];
  for (int n = n0; n < n1; ++n) {
    uint unext = 0;
    int gnext = g;
    if (n + 1 < n1) {
      unext = h[(size_t)(n + 1) * 64 + lane];
      gnext = batch[n + 1];
    }
    aLo += blo(u);
    aHi += bhi(u);
    cnt++;
    if (n + 1 < n1 && gnext != g) {
      atomicAdd(&sums[g * DD + lane * 2], aLo);
      atomicAdd(&sums[g * DD + lane * 2 + 1], aHi);
      if (lane == 0) atomicAdd(&counts[g], cnt);
      aLo = 0.f; aHi = 0.f; cnt = 0;
      g = gnext;
    }
    u = unext;
  }
  atomicAdd(&sums[g * DD + lane * 2], aLo);
  atomicAdd(&sums[g * DD + lane * 2 + 1], aHi);
  if (lane == 0) atomicAdd(&counts[g], cnt);
}

__global__ __launch_bounds__(512) void k_final(const float* __restrict__ sums,
                                               const int* __restrict__ counts,
                                               const float* __restrict__ lin_w,
                                               const float* __restrict__ lin_b,
                                               float* __restrict__ out) {
  int t = threadIdx.x;  // 512 = 64 graphs x 8 classes
  int g = t >> 3, co = t & 7;
  float cnt = (float)counts[g];
  if (cnt < 1.f) cnt = 1.f;
  float inv = 1.f / cnt;
  float v = lin_b[co];
  for (int d = 0; d < DD; ++d) v += (sums[g * DD + d] * inv) * lin_w[d * CCLS + co];
  out[t] = v;
}

extern "C" void kernel_launch(void* const* d_in, const int* in_sizes, int n_in,
                              void* d_out, int out_size, void* d_ws, size_t ws_size,
                              hipStream_t stream) {
  (void)in_sizes; (void)n_in; (void)out_size; (void)ws_size;
  const float* x     = (const float*)d_in[0];
  const float* W     = (const float*)d_in[1];
  const float* b     = (const float*)d_in[2];
  const float* lin_w = (const float*)d_in[3];
  const float* lin_b = (const float*)d_in[4];
  const int*   EI    = (const int*)d_in[5];
  const int*   batch = (const int*)d_in[6];
  float* out = (float*)d_out;

  char* ws = (char*)d_ws;
  uint*   h1    = (uint*)(ws + OFF_H1);       // bf16 packed
  ushort* WbfT  = (ushort*)(ws + OFF_WBT);
  float*  isd   = (float*)(ws + OFF_ISD);
  int*    rps   = (int*)(ws + OFF_RP);
  int*    rpc   = rps + 2 * NPAD;
  int*    ci    = (int*)(ws + OFF_CI);
  uint*   bdata = (uint*)(ws + OFF_BD);
  uint*   xw    = (uint*)(ws + OFF_XW);       // fp8 table (isd-prescaled), aliases bdata
  char*   zb    = ws + OFF_ZERO;
  int*    gcur  = (int*)(zb + ZO_GCUR);
  float*  sums  = (float*)(zb + ZO_SUM);
  int*    counts= (int*)(zb + ZO_CNT);

  (void)hipMemsetAsync(zb, 0, ZERO_BYTES, stream);

  k_wprep<<<256, 256, 0, stream>>>(W, WbfT);
  k_part<<<dim3((EE + 4095) / 4096, RR), 256, 0, stream>>>(EI, gcur, bdata);
  k_csr<<<dim3(NBUK, RR), 256, 0, stream>>>(bdata, gcur, isd, rps, rpc, ci);

  for (int l = 0; l < LL; ++l) {
    const ushort* WTl_g = WbfT + (size_t)l * RR * DD * DD;
    if (l == 0)
      k_gemm<0><<<dim3((NN + 127) / 128, RR), 256, 0, stream>>>((const void*)x, WTl_g, isd, xw);
    else
      k_gemm<1><<<dim3((NN + 127) / 128, RR), 256, 0, stream>>>((const void*)h1, WTl_g, isd, xw);
    k_agg<<<NPAD / 4, 256, 0, stream>>>((const char*)xw, rps, rpc, ci, isd,
                                        b + (size_t)l * RR * DD, h1,
                                        (l < LL - 1) ? 1 : 0);
  }
  k_pool<<<(NN + PCHUNK - 1) / PCHUNK, 64, 0, stream>>>(h1, batch, sums, counts);
  k_final<<<1, GG * CCLS, 0, stream>>>(sums, counts, lin_w, lin_b, out);
}

// Round 9
// 255.105 us; speedup vs baseline: 1.1724x; 1.1269x over previous
//
#include <hip/hip_runtime.h>
#include <math.h>

#define NN 50000
#define EE 800000
#define RR 2
#define LL 2
#define DD 128
#define GG 64
#define CCLS 8
#define NBUK 196     // buckets of 256 dst nodes: bucket = dst >> 8
#define BCAP 6144    // max edges per bucket (mean 4082, sigma 64)

typedef unsigned int uint;
typedef unsigned short ushort;
typedef short bf16x8 __attribute__((ext_vector_type(8)));
typedef float f32x4 __attribute__((ext_vector_type(4)));
typedef float f32x2 __attribute__((ext_vector_type(2)));

// ---------------- workspace layout (bytes) ----------------
#define OFF_XW    ((size_t)0)           // [2][N][128] fp8 e4m3 (isd-scaled) 12,800,000
#define OFF_H1    ((size_t)12800000)    // [N][64] uint (packed bf16)      12,800,000
#define OFF_WBT   ((size_t)25600000)    // [L][R][128][128] bf16              131,072
#define OFF_ISD   ((size_t)25731072)    // [2][N] f32                         400,000
#define OFF_RP    ((size_t)26131072)    // [2][N+1] i32                       400,064
#define OFF_CI    ((size_t)26531136)    // [2][E] i32                       6,400,000
#define OFF_BD    ((size_t)32931136)    // [2][196][6144] uint              9,633,792
#define OFF_ZERO  ((size_t)42564928)
// zero region internal offsets (bytes)
#define ZO_GCUR 0        // [2][196] i32 bucket counters (1568 B, pad 1600)
#define ZO_SUM  1600     // [G][D] f32 (32768 B)
#define ZO_CNT  34368    // [G] i32 (256 B)
#define ZERO_BYTES 34624

static __device__ __forceinline__ ushort f2b(float f) {
  uint u = __float_as_uint(f);
  uint r = (u + 0x7fffu + ((u >> 16) & 1u)) >> 16;
  return (ushort)r;
}
static __device__ __forceinline__ float blo(uint u) { return __uint_as_float(u << 16); }
static __device__ __forceinline__ float bhi(uint u) { return __uint_as_float(u & 0xffff0000u); }

// ---------------- W prep: fp32 W[l][r][k][n] -> bf16 WbfT[l][r][n][k] ----------------
__global__ __launch_bounds__(256) void k_wprep(const float* __restrict__ W,
                                               ushort* __restrict__ WT) {
  int idx = blockIdx.x * 256 + threadIdx.x;  // 65536 total
  int lr = idx >> 14;
  int rem = idx & 16383;
  int n = rem >> 7, k = rem & 127;
  WT[lr * 16384 + n * 128 + k] = f2b(W[lr * 16384 + k * 128 + n]);
}

// ---------------- phase 1: partition edges into dst buckets (coalesced) ----------------
__global__ __launch_bounds__(256) void k_part(const int* __restrict__ EI,
                                              int* __restrict__ gcur,
                                              uint* __restrict__ bdata) {
  __shared__ int hist[256];   // bucket counts -> stage-exclusive offsets
  __shared__ int sbase[256];  // scan scratch
  __shared__ int gbase[256];  // global reservation base per bucket
  __shared__ int lcur[256];
  __shared__ uint stage[4096];
  __shared__ unsigned char bstage[4096];
  const int r = blockIdx.y;
  const int t = threadIdx.x;
  const int e0 = blockIdx.x * 4096;
  const int cnt = min(4096, EE - e0);
  hist[t] = 0;
  lcur[t] = 0;
  __syncthreads();

  int src[16], dst[16];
  bool val[4];
#pragma unroll
  for (int j = 0; j < 4; ++j) {
    int i4 = (j * 256 + t) * 4;
    val[j] = (i4 < cnt);
    if (val[j]) {
      int4 s4 = *(const int4*)(EI + (size_t)r * 2 * EE + e0 + i4);
      int4 d4 = *(const int4*)(EI + (size_t)r * 2 * EE + EE + e0 + i4);
      src[j * 4 + 0] = s4.x; src[j * 4 + 1] = s4.y; src[j * 4 + 2] = s4.z; src[j * 4 + 3] = s4.w;
      dst[j * 4 + 0] = d4.x; dst[j * 4 + 1] = d4.y; dst[j * 4 + 2] = d4.z; dst[j * 4 + 3] = d4.w;
#pragma unroll
      for (int i = 0; i < 4; ++i) atomicAdd(&hist[dst[j * 4 + i] >> 8], 1);
    }
  }
  __syncthreads();
  int hv = hist[t];
  if (t < NBUK && hv > 0)
    gbase[t] = atomicAdd(&gcur[r * NBUK + t], hv);
  else
    gbase[t] = 0;
  sbase[t] = hv;
  __syncthreads();
  for (int off = 1; off < 256; off <<= 1) {
    int u = (t >= off) ? sbase[t - off] : 0;
    __syncthreads();
    sbase[t] += u;
    __syncthreads();
  }
  int incl = sbase[t];
  hist[t] = incl - hv;  // exclusive stage offset
  __syncthreads();
#pragma unroll
  for (int j = 0; j < 4; ++j) {
    if (val[j]) {
#pragma unroll
      for (int i = 0; i < 4; ++i) {
        int d = dst[j * 4 + i];
        int b = d >> 8;
        int p = atomicAdd(&lcur[b], 1);
        int pos = hist[b] + p;
        stage[pos] = ((uint)src[j * 4 + i] << 8) | (uint)(d & 255);
        bstage[pos] = (unsigned char)b;
      }
    }
  }
  __syncthreads();
  for (int s = t; s < cnt; s += 256) {
    int b = (int)bstage[s];
    bdata[(size_t)(r * NBUK + b) * BCAP + gbase[b] + (s - hist[b])] = stage[s];
  }
}

// ---------------- phase 2: per-bucket CSR (deg, isd, rp, ci) all coalesced ----------------
__global__ __launch_bounds__(256) void k_csr(const uint* __restrict__ bdata,
                                             const int* __restrict__ gcur,
                                             float* __restrict__ isd,
                                             int* __restrict__ rp,
                                             int* __restrict__ ci) {
  __shared__ int lcnt[256];
  __shared__ int lrp[256];
  __shared__ int lcur[256];
  __shared__ int cstage[BCAP];
  __shared__ int basesh;
  const int b = blockIdx.x;
  const int r = blockIdx.y;
  const int t = threadIdx.x;
  const int cnt = gcur[r * NBUK + b];
  // bucket base = prefix sum of gcur[r][0..b-1] (NBUK <= 256: 1 elem/thread)
  lcnt[t] = (t < b) ? gcur[r * NBUK + t] : 0;
  __syncthreads();
  for (int off = 128; off > 0; off >>= 1) {
    if (t < off) lcnt[t] += lcnt[t + off];
    __syncthreads();
  }
  if (t == 0) basesh = lcnt[0];
  __syncthreads();
  const int base = basesh;
  const uint* bd = bdata + (size_t)(r * NBUK + b) * BCAP;
  __syncthreads();
  lcnt[t] = 0;
  lcur[t] = 0;
  __syncthreads();
  for (int s = t; s < cnt; s += 256) {
    uint pr = bd[s];
    atomicAdd(&lcnt[pr & 255u], 1);
  }
  __syncthreads();
  int deg = lcnt[t];
  lrp[t] = deg;
  __syncthreads();
  for (int off = 1; off < 256; off <<= 1) {
    int u = (t >= off) ? lrp[t - off] : 0;
    __syncthreads();
    lrp[t] += u;
    __syncthreads();
  }
  int incl = lrp[t];
  __syncthreads();
  lrp[t] = incl - deg;  // exclusive
  __syncthreads();
  int node = b * 256 + t;
  if (node < NN) {
    isd[r * NN + node] = rsqrtf((float)(deg + 1));
    rp[r * (NN + 1) + node] = base + lrp[t];
  }
  if (b == NBUK - 1 && t == 0) rp[r * (NN + 1) + NN] = EE;
  for (int s = t; s < cnt; s += 256) {
    uint pr = bd[s];
    int j = (int)(pr & 255u);
    int p = atomicAdd(&lcur[j], 1);
    cstage[lrp[j] + p] = (int)(pr >> 8);
  }
  __syncthreads();
  for (int s = t; s < cnt; s += 256) ci[(size_t)r * EE + base + s] = cstage[s];
}

// ---------------- MFMA GEMM, merged relations: block stages A once, loops r ----------------
// xw'[r][m][:] = (X[m][:] @ W[r]) * isd[r][m], fp8 out. A-tile (128x128 bf16) staged
// ONCE per block and reused for both relations (halves X traffic vs per-relation grids).
#define AL2_S 136   // 128+8 bf16 row stride (34,816 B)
#define WT2_S 72    // 64+8 bf16 row stride (18,432 B)
template <int IN_BF16>
__global__ __launch_bounds__(256) void k_gemm(const void* __restrict__ Xv,
                                              const ushort* __restrict__ WTg,
                                              const float* __restrict__ isd,
                                              uint* __restrict__ Y) {
  __shared__ ushort Al[128 * AL2_S];
  __shared__ ushort WTl[128 * WT2_S];
  const int m0b = blockIdx.x * 128;
  const int t = threadIdx.x;
  const int w = t >> 6, L = t & 63, q = L >> 4, ln = L & 15;

  // stage full A tile: 128 rows x 128 ch (thread: row t>>1, 64-ch half t&1)
  {
    int row = t >> 1, ch0 = (t & 1) * 64;
    int gm = m0b + row;
    ushort* dst = &Al[row * AL2_S + ch0];
    if (gm < NN) {
      if (IN_BF16) {
        const uint4* xp = (const uint4*)((const ushort*)Xv + (size_t)gm * 128 + ch0);
#pragma unroll
        for (int j = 0; j < 8; ++j) ((uint4*)dst)[j] = xp[j];
      } else {
        const float4* xp = (const float4*)((const float*)Xv + (size_t)gm * 128 + ch0);
#pragma unroll
        for (int j = 0; j < 16; ++j) {
          float4 v = xp[j];
          dst[j * 4 + 0] = f2b(v.x); dst[j * 4 + 1] = f2b(v.y);
          dst[j * 4 + 2] = f2b(v.z); dst[j * 4 + 3] = f2b(v.w);
        }
      }
    } else {
      uint4 z = make_uint4(0, 0, 0, 0);
#pragma unroll
      for (int j = 0; j < 8; ++j) ((uint4*)dst)[j] = z;
    }
  }

#pragma unroll
  for (int r = 0; r < RR; ++r) {
    const ushort* WTr = WTg + (size_t)r * 16384;
    uint* Yr = Y + (size_t)r * NN * 32;   // fp8 row = 32 uints

    f32x4 acc[2][8];
#pragma unroll
    for (int mt = 0; mt < 2; ++mt)
#pragma unroll
      for (int nt = 0; nt < 8; ++nt) {
        acc[mt][nt][0] = 0.f; acc[mt][nt][1] = 0.f;
        acc[mt][nt][2] = 0.f; acc[mt][nt][3] = 0.f;
      }

    for (int hh = 0; hh < 2; ++hh) {
      __syncthreads();   // A visible (first pass) / prior MFMA reads of WTl done
      {
        int n = t >> 1, k0 = (t & 1) * 32;   // stage WT half: 128 n x 64 k
#pragma unroll
        for (int j = 0; j < 4; ++j)
          *(uint4*)(&WTl[n * WT2_S + k0 + j * 8]) =
              *(const uint4*)(WTr + n * 128 + hh * 64 + k0 + j * 8);
      }
      __syncthreads();
#pragma unroll
      for (int kk = 0; kk < 2; ++kk) {
        bf16x8 b0 = *(const bf16x8*)(&Al[(w * 32 + ln) * AL2_S + hh * 64 + kk * 32 + q * 8]);
        bf16x8 b1 = *(const bf16x8*)(&Al[(w * 32 + 16 + ln) * AL2_S + hh * 64 + kk * 32 + q * 8]);
#pragma unroll
        for (int nt = 0; nt < 8; ++nt) {
          bf16x8 a = *(const bf16x8*)(&WTl[(nt * 16 + ln) * WT2_S + kk * 32 + q * 8]);
          acc[0][nt] = __builtin_amdgcn_mfma_f32_16x16x32_bf16(a, b0, acc[0][nt], 0, 0, 0);
          acc[1][nt] = __builtin_amdgcn_mfma_f32_16x16x32_bf16(a, b1, acc[1][nt], 0, 0, 0);
        }
      }
    }
    // epilogue r: lane holds D for m = m0b + w*32 + mt*16 + ln, n = nt*16 + q*4 + reg
#pragma unroll
    for (int mt = 0; mt < 2; ++mt) {
      int m = m0b + w * 32 + mt * 16 + ln;
      if (m < NN) {
        float sc = isd[r * NN + m];
        uint* yp = Yr + (size_t)m * 32;
#pragma unroll
        for (int nt = 0; nt < 8; ++nt) {
          f32x4 v = acc[mt][nt];
          uint u = __builtin_amdgcn_cvt_pk_fp8_f32(v[0] * sc, v[1] * sc, 0u, false);
          u = __builtin_amdgcn_cvt_pk_fp8_f32(v[2] * sc, v[3] * sc, u, true);
          yp[nt * 4 + q] = u;
        }
      }
    }
  }
}

// ---------------- aggregation: 1 wave/node, 8 edges in flight, uint4 gathers ----------------
// lane = g*8 + c: g = edge slot (0..7), c = channel quad (16 fp8 channels = 1 uint4).
// out[i] = sum_r di_r * (sum_e xw'[src_e] + xw'[i]) + bias   (xw' is isd-prescaled)
// EXACT round-0 structure (measured 47.6 us): conditional gathers, depth-1 + index-ahead.
__global__ __launch_bounds__(256) void k_agg(const uint4* __restrict__ xw4,
                                             const int* __restrict__ rp,
                                             const int* __restrict__ ci,
                                             const float* __restrict__ isd,
                                             const float* __restrict__ bias,
                                             uint* __restrict__ hout, int relu_flag) {
  const int w = threadIdx.x >> 6;
  const int lane = threadIdx.x & 63;
  const int g = lane >> 3, c = lane & 7;
  const int i = blockIdx.x * 4 + w;

  float tot[16];
#pragma unroll
  for (int k = 0; k < 16; ++k) tot[k] = 0.f;

#pragma unroll
  for (int r = 0; r < RR; ++r) {
    const uint4* xwr = xw4 + (size_t)r * NN * 8;  // 8 uint4 per row
    const int* cir = ci + (size_t)r * EE;
    const float di = isd[r * NN + i];
    const int e0 = rp[r * (NN + 1) + i];
    const int cnt = rp[r * (NN + 1) + i + 1] - e0;
    const int total = cnt + 1;  // + self (virtual edge idx == cnt, s = i)

    float acc[16];
#pragma unroll
    for (int k = 0; k < 16; ++k) acc[k] = 0.f;

    int s_cur = (g < cnt) ? cir[e0 + g] : i;
    for (int base = 0; base < total; base += 8) {
      int idxn = base + 8 + g;
      int s_next = (idxn < cnt) ? cir[e0 + idxn] : i;  // prefetch next slot's index
      if (base + g < total) {
        uint4 u = xwr[(size_t)s_cur * 8 + c];
        f32x2 v;
        v = __builtin_amdgcn_cvt_pk_f32_fp8(u.x, false); acc[0] += v[0];  acc[1] += v[1];
        v = __builtin_amdgcn_cvt_pk_f32_fp8(u.x, true);  acc[2] += v[0];  acc[3] += v[1];
        v = __builtin_amdgcn_cvt_pk_f32_fp8(u.y, false); acc[4] += v[0];  acc[5] += v[1];
        v = __builtin_amdgcn_cvt_pk_f32_fp8(u.y, true);  acc[6] += v[0];  acc[7] += v[1];
        v = __builtin_amdgcn_cvt_pk_f32_fp8(u.z, false); acc[8] += v[0];  acc[9] += v[1];
        v = __builtin_amdgcn_cvt_pk_f32_fp8(u.z, true);  acc[10] += v[0]; acc[11] += v[1];
        v = __builtin_amdgcn_cvt_pk_f32_fp8(u.w, false); acc[12] += v[0]; acc[13] += v[1];
        v = __builtin_amdgcn_cvt_pk_f32_fp8(u.w, true);  acc[14] += v[0]; acc[15] += v[1];
      }
      s_cur = s_next;
    }
#pragma unroll
    for (int k = 0; k < 16; ++k) tot[k] = fmaf(di, acc[k], tot[k]);
  }

  // reduce over the 8 edge slots (lane bits 3,4,5)
#pragma unroll
  for (int mask = 8; mask <= 32; mask <<= 1) {
#pragma unroll
    for (int k = 0; k < 16; ++k) tot[k] += __shfl_xor(tot[k], mask);
  }

  // lanes g<2 write: lane (g,c) stores channels [c*16 + g*8, +8) as 4 packed uints
  if (g < 2) {
    int ch0 = c * 16 + g * 8;
    const float4* bp = (const float4*)(bias + ch0);
    const float4* bq = (const float4*)(bias + DD + ch0);
    float4 b0 = bp[0], b1 = bp[1], b2 = bq[0], b3 = bq[1];
    float o[8];
#pragma unroll
    for (int j = 0; j < 8; ++j) o[j] = (g == 0) ? tot[j] : tot[8 + j];
    o[0] += b0.x + b2.x; o[1] += b0.y + b2.y; o[2] += b0.z + b2.z; o[3] += b0.w + b2.w;
    o[4] += b1.x + b3.x; o[5] += b1.y + b3.y; o[6] += b1.z + b3.z; o[7] += b1.w + b3.w;
    if (relu_flag) {
#pragma unroll
      for (int j = 0; j < 8; ++j) o[j] = fmaxf(o[j], 0.f);
    }
    uint4 pk;
    pk.x = (uint)f2b(o[0]) | ((uint)f2b(o[1]) << 16);
    pk.y = (uint)f2b(o[2]) | ((uint)f2b(o[3]) << 16);
    pk.z = (uint)f2b(o[4]) | ((uint)f2b(o[5]) << 16);
    pk.w = (uint)f2b(o[6]) | ((uint)f2b(o[7]) << 16);
    ((uint4*)(hout + (size_t)i * 64))[c * 2 + g] = pk;
  }
}

// ---------------- pooling (batch ids sorted), packed bf16 input ----------------
#define PCHUNK 32
__global__ __launch_bounds__(64) void k_pool(const uint* __restrict__ h,
                                             const int* __restrict__ batch,
                                             float* __restrict__ sums,
                                             int* __restrict__ counts) {
  int lane = threadIdx.x;
  int n0 = blockIdx.x * PCHUNK;
  int n1 = n0 + PCHUNK;
  if (n1 > NN) n1 = NN;
  if (n0 >= NN) return;
  float aLo = 0.f, aHi = 0.f;
  int cnt = 0;
  int g = batch[n0];
  uint u = h[(size_t)n0 * 64 + lane];
  for (int n = n0; n < n1; ++n) {
    uint unext = 0;
    int gnext = g;
    if (n + 1 < n1) {
      unext = h[(size_t)(n + 1) * 64 + lane];
      gnext = batch[n + 1];
    }
    aLo += blo(u);
    aHi += bhi(u);
    cnt++;
    if (n + 1 < n1 && gnext != g) {
      atomicAdd(&sums[g * DD + lane * 2], aLo);
      atomicAdd(&sums[g * DD + lane * 2 + 1], aHi);
      if (lane == 0) atomicAdd(&counts[g], cnt);
      aLo = 0.f; aHi = 0.f; cnt = 0;
      g = gnext;
    }
    u = unext;
  }
  atomicAdd(&sums[g * DD + lane * 2], aLo);
  atomicAdd(&sums[g * DD + lane * 2 + 1], aHi);
  if (lane == 0) atomicAdd(&counts[g], cnt);
}

// ---------------- final linear: 1 block per graph, wave-parallel over D ----------------
__global__ __launch_bounds__(64) void k_final(const float* __restrict__ sums,
                                              const int* __restrict__ counts,
                                              const float* __restrict__ lin_w,
                                              const float* __restrict__ lin_b,
                                              float* __restrict__ out) {
  const int g = blockIdx.x;         // 64 graphs
  const int t = threadIdx.x;        // 64
  const int co = t & 7, dp = t >> 3;  // 8 d-groups x 8 classes
  float p = 0.f;
#pragma unroll
  for (int j = 0; j < 16; ++j) {
    int d = dp + 8 * j;
    p += sums[g * DD + d] * lin_w[d * CCLS + co];
  }
#pragma unroll
  for (int mask = 8; mask <= 32; mask <<= 1) p += __shfl_xor(p, mask);
  if (t < 8) {
    float cnt = (float)counts[g];
    if (cnt < 1.f) cnt = 1.f;
    out[g * CCLS + t] = p / cnt + lin_b[t];
  }
}

extern "C" void kernel_launch(void* const* d_in, const int* in_sizes, int n_in,
                              void* d_out, int out_size, void* d_ws, size_t ws_size,
                              hipStream_t stream) {
  (void)in_sizes; (void)n_in; (void)out_size; (void)ws_size;
  const float* x     = (const float*)d_in[0];
  const float* W     = (const float*)d_in[1];
  const float* b     = (const float*)d_in[2];
  const float* lin_w = (const float*)d_in[3];
  const float* lin_b = (const float*)d_in[4];
  const int*   EI    = (const int*)d_in[5];
  const int*   batch = (const int*)d_in[6];
  float* out = (float*)d_out;

  char* ws = (char*)d_ws;
  uint*   xw    = (uint*)(ws + OFF_XW);       // fp8 table (isd-prescaled)
  uint*   h1    = (uint*)(ws + OFF_H1);       // bf16 packed
  ushort* WbfT  = (ushort*)(ws + OFF_WBT);
  float*  isd   = (float*)(ws + OFF_ISD);
  int*    rp    = (int*)(ws + OFF_RP);
  int*    ci    = (int*)(ws + OFF_CI);
  uint*   bdata = (uint*)(ws + OFF_BD);
  char*   zb    = ws + OFF_ZERO;
  int*    gcur  = (int*)(zb + ZO_GCUR);
  float*  sums  = (float*)(zb + ZO_SUM);
  int*    counts= (int*)(zb + ZO_CNT);

  (void)hipMemsetAsync(zb, 0, ZERO_BYTES, stream);

  k_wprep<<<256, 256, 0, stream>>>(W, WbfT);
  k_part<<<dim3((EE + 4095) / 4096, RR), 256, 0, stream>>>(EI, gcur, bdata);
  k_csr<<<dim3(NBUK, RR), 256, 0, stream>>>(bdata, gcur, isd, rp, ci);

  for (int l = 0; l < LL; ++l) {
    const ushort* WTl_g = WbfT + (size_t)l * RR * DD * DD;
    if (l == 0)
      k_gemm<0><<<(NN + 127) / 128, 256, 0, stream>>>((const void*)x, WTl_g, isd, xw);
    else
      k_gemm<1><<<(NN + 127) / 128, 256, 0, stream>>>((const void*)h1, WTl_g, isd, xw);
    k_agg<<<(NN + 3) / 4, 256, 0, stream>>>((const uint4*)xw, rp, ci, isd,
                                            b + (size_t)l * RR * DD, h1,
                                            (l < LL - 1) ? 1 : 0);
  }
  k_pool<<<(NN + PCHUNK - 1) / PCHUNK, 64, 0, stream>>>(h1, batch, sums, counts);
  k_final<<<GG, 64, 0, stream>>>(sums, counts, lin_w, lin_b, out);
}